// Round 1
// 1611.673 us; speedup vs baseline: 1.1800x; 1.1800x over previous
//
#include <hip/hip_runtime.h>
#include <stdint.h>

// Problem constants
#define N4   4096
#define H0   256
#define SIDE 1024
#define DIN  512
#define HCAT 768      // H0 + DIN
#define H1   128
#define NC   5
#define NUV  16777216ULL   // 4096*4096
#define CAP  1536          // max compacted entries per row

typedef __attribute__((ext_vector_type(8))) short short8;    // 8 bf16
typedef __attribute__((ext_vector_type(4))) float floatx4;

__device__ __forceinline__ unsigned short f2bf(float f) {
    unsigned int u;
    __builtin_memcpy(&u, &f, 4);
    unsigned int r = (u + 0x7FFFu + ((u >> 16) & 1u)) >> 16;   // RNE
    return (unsigned short)r;
}

// ---------------------------------------------------------------- k_counts
__global__ __launch_bounds__(256) void k_counts(const int* __restrict__ u,
                                                const int* __restrict__ v,
                                                int* __restrict__ cu,
                                                int* __restrict__ cv) {
    int i = blockIdx.x * 256 + threadIdx.x;   // 4096 threads
    atomicAdd(&cu[u[i]], 1);
    atomicAdd(&cv[v[i]], 1);
}

// ---------------------------------------------------------------- k_code
__global__ __launch_bounds__(256) void k_code(const float* __restrict__ adj,
                                              uchar4* __restrict__ code4) {
    size_t g = (size_t)blockIdx.x * 256 + threadIdx.x;
    size_t base = g * 4;
    uchar4 out = {0, 0, 0, 0};
    #pragma unroll
    for (int c = 0; c < NC; c++) {
        float4 s = *(const float4*)(adj + (size_t)c * NUV + base);
        out.x = (s.x != 0.f) ? (unsigned char)(c + 1) : out.x;
        out.y = (s.y != 0.f) ? (unsigned char)(c + 1) : out.y;
        out.z = (s.z != 0.f) ? (unsigned char)(c + 1) : out.z;
        out.w = (s.w != 0.f) ? (unsigned char)(c + 1) : out.w;
    }
    code4[g] = out;
}

// ---------------------------------------------------------------- k_transpose (byte, 64x64 tiles)
__global__ __launch_bounds__(256) void k_transpose(const uint8_t* __restrict__ src,
                                                   uint8_t* __restrict__ dst) {
    __shared__ __align__(16) uint8_t tile[64][80];
    int t = threadIdx.x;
    int row = t >> 2;
    int seg = (t & 3) * 16;
    int p0 = blockIdx.y * 64, q0 = blockIdx.x * 64;
    uint4 vdat = *(const uint4*)(src + (size_t)(p0 + row) * N4 + q0 + seg);
    *(uint4*)(&tile[row][seg]) = vdat;
    __syncthreads();
    union { uint4 u4; uint8_t b[16]; } o;
    #pragma unroll
    for (int l = 0; l < 16; l++) o.b[l] = tile[seg + l][row];
    *(uint4*)(dst + (size_t)(q0 + row) * N4 + p0 + seg) = o.u4;
}

// ---------------------------------------------------------------- k_wcumsum
// out[r][node][h] = f16( cnt[node] * cumsum_r(w)[r][node][h] )
__global__ __launch_bounds__(256) void k_wcumsum(const float* __restrict__ w,
                                                 const int* __restrict__ cnt,
                                                 unsigned short* __restrict__ out) {
    int node = blockIdx.x, h = threadIdx.x;
    float c = (float)cnt[node];
    float acc = 0.f;
    #pragma unroll
    for (int r = 0; r < NC; r++) {
        size_t idx = ((size_t)r * N4 + node) * H0 + h;
        acc += w[idx];
        union { _Float16 h16; unsigned short s; } cvt;
        cvt.h16 = (_Float16)(acc * c);
        out[idx] = cvt.s;
    }
}

// ---------------------------------------------------------------- k_compact
// Compact one code row into entry list (ushort: (r-1)*4096+q), plus
// deg[p] and nnz[p]. Shfl-based scan: 2 barriers total.
__global__ __launch_bounds__(256) void k_compact(const uint8_t* __restrict__ codeRows,
                                                 const int* __restrict__ cntOther,
                                                 unsigned short* __restrict__ idx,
                                                 int* __restrict__ nnz,
                                                 float* __restrict__ deg) {
    __shared__ float cw[4096];
    __shared__ int wtot[4];
    __shared__ float wdeg[4];
    __shared__ unsigned short ebuf[CAP];
    int p = blockIdx.x, t = threadIdx.x;
    int lane = t & 63, wv = t >> 6;
    const int4* co4 = (const int4*)cntOther;
    #pragma unroll
    for (int l = 0; l < 4; l++) {
        int4 ci = co4[t + l * 256];
        ((float4*)cw)[t + l * 256] =
            make_float4((float)ci.x, (float)ci.y, (float)ci.z, (float)ci.w);
    }
    uint4 w = ((const uint4*)(codeRows + (size_t)p * N4))[t];
    unsigned char b[16];
    __builtin_memcpy(b, &w, 16);
    int cnt = 0;
    #pragma unroll
    for (int j = 0; j < 16; j++) cnt += (b[j] != 0);
    // wave-level inclusive scan (no barriers)
    int sc = cnt;
    #pragma unroll
    for (int off = 1; off < 64; off <<= 1) {
        int up = __shfl_up(sc, off, 64);
        if (lane >= off) sc += up;
    }
    if (lane == 63) wtot[wv] = sc;
    __syncthreads();            // covers cw + wtot
    int wbase = 0;
    #pragma unroll
    for (int ww = 0; ww < 4; ww++) wbase += (ww < wv) ? wtot[ww] : 0;
    int total = wtot[0] + wtot[1] + wtot[2] + wtot[3];
    int pos = wbase + sc - cnt;   // block-exclusive prefix
    float dsum = 0.f;
    #pragma unroll
    for (int j = 0; j < 16; j++) {
        int r = b[j];
        if (r) {
            int q = t * 16 + j;
            if (pos < CAP) ebuf[pos] = (unsigned short)((r - 1) * N4 + q);
            pos++;
            dsum += cw[q];
        }
    }
    #pragma unroll
    for (int off = 32; off; off >>= 1) dsum += __shfl_down(dsum, off, 64);
    if (lane == 0) wdeg[wv] = dsum;
    __syncthreads();            // covers ebuf + wdeg
    int tw = total < CAP ? total : CAP;
    if (t == 0) { deg[p] = wdeg[0] + wdeg[1] + wdeg[2] + wdeg[3]; nnz[p] = tw; }
    for (int e = t; e < tw; e += 256) idx[(size_t)p * CAP + e] = ebuf[e];
}

// ---------------------------------------------------------------- k_gather2
__global__ __launch_bounds__(256) void k_gather2(const unsigned short* __restrict__ idx,
                                                 const int* __restrict__ nnz,
                                                 const unsigned short* __restrict__ tbl,
                                                 float* __restrict__ outNN) {
    __shared__ unsigned short sidx[256];
    __shared__ float red[512];
    int p = blockIdx.x, t = threadIdx.x;
    int n = nnz[p];
    int half = t >> 7, hp = t & 127;
    const char* tb = (const char*)tbl;
    const unsigned short* rowIdx = idx + (size_t)p * CAP;
    float a0 = 0.f, a1 = 0.f;
    for (int base = 0; base < n; base += 256) {
        int m = n - base; if (m > 256) m = 256;
        if (t < m) sidx[t] = rowIdx[base + t];
        __syncthreads();
        for (int e = half; e < m; e += 2) {
            int off = ((int)sidx[e]) << 9;          // *512 bytes per table row
            unsigned d = *(const unsigned*)(tb + off + hp * 4);
            union { unsigned u; _Float16 h[2]; } cv; cv.u = d;
            a0 += (float)cv.h[0];
            a1 += (float)cv.h[1];
        }
        __syncthreads();
    }
    red[t] = a0; red[256 + t] = a1;
    __syncthreads();
    if (t < 128) {
        float r0 = red[t] + red[128 + t];
        float r1 = red[256 + t] + red[384 + t];
        *(float2*)(outNN + (size_t)p * H0 + 2 * hp) = make_float2(r0, r1);
    }
}

// ---------------------------------------------------------------- k_reorder
// codeR[i][j] = code[u[i]][v[j]]
__global__ __launch_bounds__(256) void k_reorder(const uint8_t* __restrict__ code,
                                                 const int* __restrict__ u,
                                                 const int* __restrict__ v,
                                                 uint8_t* __restrict__ codeR) {
    __shared__ __align__(16) uint8_t rowbuf[4096];
    int i = blockIdx.x, t = threadIdx.x;
    int urow = u[i];
    ((uint4*)rowbuf)[t] = ((const uint4*)(code + (size_t)urow * N4))[t];
    __syncthreads();
    uint8_t ob[16];
    #pragma unroll
    for (int w = 0; w < 4; w++) {
        int4 vv = ((const int4*)v)[t * 4 + w];
        ob[w * 4 + 0] = rowbuf[vv.x];
        ob[w * 4 + 1] = rowbuf[vv.y];
        ob[w * 4 + 2] = rowbuf[vv.z];
        ob[w * 4 + 3] = rowbuf[vv.w];
    }
    uint4 o;
    __builtin_memcpy(&o, ob, 16);
    ((uint4*)(codeR + (size_t)i * N4))[t] = o;
}

// ---------------------------------------------------------------- k_z
__global__ __launch_bounds__(256) void k_z(const float* __restrict__ nn,
                                           const int* __restrict__ idxs,
                                           const int* __restrict__ idxo,
                                           const float* __restrict__ deg,
                                           float* __restrict__ cat) {
    int i = blockIdx.x, h = threadIdx.x;
    float d = deg[idxo[i]];
    float inv = d > 0.f ? 1.f / d : 0.f;
    float val = nn[(size_t)idxs[i] * H0 + h] * inv;
    cat[(size_t)i * HCAT + h] = fmaxf(val, 0.f);
}

// ---------------------------------------------------------------- generic NT GEMM (fp32 in, fp32 or bf16 out)
template <int TM, int TN, int BK, int RM, int RN, bool GATHER, bool BIAS, bool RELU, bool BF16OUT>
__global__ __launch_bounds__(256) void k_gemm(const float* __restrict__ A, int lda,
                                              const int* __restrict__ rowmap,
                                              const float* __restrict__ B, int ldb,
                                              const float* __restrict__ bias,
                                              float* __restrict__ C, int ldc, int K,
                                              size_t bzs, size_t czs) {
    constexpr int TX = TN / RN;
    constexpr int TY = TM / RM;
    static_assert(TX * TY == 256, "block must be 256");
    __shared__ float As[BK][TM + 4];
    __shared__ float Bs[BK][TN + 4];
    int tid = threadIdx.x;
    int tx = tid % TX, ty = tid / TX;
    int i0 = blockIdx.x * TM, n0 = blockIdx.y * TN;
    const float* Bz = B + (size_t)blockIdx.z * bzs;
    float acc[RM][RN] = {};
    for (int k0 = 0; k0 < K; k0 += BK) {
        for (int g = tid; g < TM * BK / 4; g += 256) {
            int i = g / (BK / 4), kc = g % (BK / 4);
            int row = GATHER ? rowmap[i0 + i] : (i0 + i);
            float4 val = *(const float4*)(A + (size_t)row * lda + k0 + kc * 4);
            As[kc * 4 + 0][i] = val.x; As[kc * 4 + 1][i] = val.y;
            As[kc * 4 + 2][i] = val.z; As[kc * 4 + 3][i] = val.w;
        }
        for (int g = tid; g < TN * BK / 4; g += 256) {
            int n = g / (BK / 4), kc = g % (BK / 4);
            float4 val = *(const float4*)(Bz + (size_t)(n0 + n) * ldb + k0 + kc * 4);
            Bs[kc * 4 + 0][n] = val.x; Bs[kc * 4 + 1][n] = val.y;
            Bs[kc * 4 + 2][n] = val.z; Bs[kc * 4 + 3][n] = val.w;
        }
        __syncthreads();
        #pragma unroll
        for (int k = 0; k < BK; k++) {
            float av[RM], bv[RN];
            #pragma unroll
            for (int m = 0; m < RM; m++) av[m] = As[k][ty * RM + m];
            #pragma unroll
            for (int n = 0; n < RN; n++) bv[n] = Bs[k][tx * RN + n];
            #pragma unroll
            for (int m = 0; m < RM; m++)
                #pragma unroll
                for (int n = 0; n < RN; n++)
                    acc[m][n] = fmaf(av[m], bv[n], acc[m][n]);
        }
        __syncthreads();
    }
    #pragma unroll
    for (int m = 0; m < RM; m++) {
        int ig = i0 + ty * RM + m;
        #pragma unroll
        for (int n = 0; n < RN; n++) {
            float vv = acc[m][n];
            if (BIAS) vv += bias[n0 + tx * RN + n];
            if (RELU) vv = fmaxf(vv, 0.f);
            if (BF16OUT) {
                unsigned short* Cz16 = (unsigned short*)C + (size_t)blockIdx.z * czs;
                Cz16[(size_t)ig * ldc + n0 + tx * RN + n] = f2bf(vv);
            } else {
                float* Cz = C + (size_t)blockIdx.z * czs;
                Cz[(size_t)ig * ldc + n0 + tx * RN + n] = vv;
            }
        }
    }
}

// ---------------------------------------------------------------- k_Pt : Pt[b][e][d] = P[b][d][e]
__global__ __launch_bounds__(256) void k_Pt(const float* __restrict__ P, float* __restrict__ Pt) {
    int tid = blockIdx.x * 256 + threadIdx.x;   // 32768
    int b = tid >> 14;
    int d = (tid >> 7) & 127;
    int e = tid & 127;
    Pt[((size_t)b * 128 + e) * 128 + d] = P[tid];
}

// ---------------------------------------------------------------- k_scores3 (MFMA bf16 decoder + softmax epilogue)
// Tile: 64 i x 128 j per block (4 waves, one 16-row strip each). No LDS.
// A frag: tb[b][i0+lr][kc*32+lk*8 ..+8]; B frag: vhb[jb+lr][kc*32+lk*8 ..+8]
// C/D: col=lane&15, row=(lane>>4)*4+reg (m89-verified layout).
// Loss partials: wave shfl-reduce -> LDS -> ONE slot per block in part[].
// (v2: contended same-address atomicAdd burst from 8192 co-resident waves
//  was serializing ~24k RMWs at kernel end -> replaced by private partials.)
__global__ __launch_bounds__(256) void k_scores3(const unsigned short* __restrict__ tb,  // [2][4096][128] bf16
                                                 const unsigned short* __restrict__ vhb, // [4096][128] bf16
                                                 const uint8_t* __restrict__ codeR,
                                                 const float* __restrict__ a_f,          // [2][5]
                                                 float* __restrict__ mhat,
                                                 float* __restrict__ part) {
    __shared__ float wred[4][3];
    int t = threadIdx.x;
    int wave = t >> 6, lane = t & 63;
    int lr = lane & 15;          // A row / B col / C col
    int lk = lane >> 4;          // k-subgroup & C row-group
    int i0 = blockIdx.y * 64 + wave * 16;
    int j0 = blockIdx.x * 128;
    float sa0[NC], sa1[NC];
    #pragma unroll
    for (int c = 0; c < NC; c++) { sa0[c] = a_f[c]; sa1[c] = a_f[5 + c]; }

    const unsigned short* t0p = tb;
    const unsigned short* t1p = tb + (size_t)N4 * H1;
    short8 a0[4], a1[4];
    #pragma unroll
    for (int kc = 0; kc < 4; kc++) {
        size_t off = (size_t)(i0 + lr) * H1 + kc * 32 + lk * 8;
        a0[kc] = *(const short8*)(t0p + off);
        a1[kc] = *(const short8*)(t1p + off);
    }

    float lsum = 0.f, ssum = 0.f, nobs = 0.f;
    for (int jt = 0; jt < 8; jt++) {
        int jb = j0 + jt * 16;
        int j = jb + lr;
        // hoist codeR loads above the MFMAs so HBM latency overlaps compute
        const uint8_t* crp = codeR + (size_t)(i0 + lk * 4) * N4 + j;
        int cbv[4];
        cbv[0] = crp[0];
        cbv[1] = crp[N4];
        cbv[2] = crp[2 * N4];
        cbv[3] = crp[3 * N4];
        floatx4 C0 = {0.f, 0.f, 0.f, 0.f}, C1 = {0.f, 0.f, 0.f, 0.f};
        #pragma unroll
        for (int kc = 0; kc < 4; kc++) {
            short8 b = *(const short8*)(vhb + (size_t)(jb + lr) * H1 + kc * 32 + lk * 8);
            C0 = __builtin_amdgcn_mfma_f32_16x16x32_bf16(a0[kc], b, C0, 0, 0, 0);
            C1 = __builtin_amdgcn_mfma_f32_16x16x32_bf16(a1[kc], b, C1, 0, 0, 0);
        }
        #pragma unroll
        for (int r = 0; r < 4; r++) {
            int i = i0 + lk * 4 + r;
            float v0 = C0[r], v1 = C1[r];
            float l[NC];
            float mx = -1e30f;
            #pragma unroll
            for (int c = 0; c < NC; c++) {
                l[c] = sa0[c] * v0 + sa1[c] * v1;
                mx = fmaxf(mx, l[c]);
            }
            float den = 0.f, num = 0.f;
            #pragma unroll
            for (int c = 0; c < NC; c++) {
                float e = __expf(l[c] - mx);
                den += e;
                num += (float)(c + 1) * e;
            }
            float mh = num / den;
            mhat[(size_t)i * N4 + j] = mh;
            int cb = cbv[r];
            if (cb) {
                float lse = mx + __logf(den);
                lsum += lse - l[cb - 1];        // = -logp[cb-1]
                float df = mh - (float)cb;
                ssum += df * df;
                nobs += 1.f;
            }
        }
    }
    #pragma unroll
    for (int off = 32; off; off >>= 1) {
        lsum += __shfl_down(lsum, off, 64);
        ssum += __shfl_down(ssum, off, 64);
        nobs += __shfl_down(nobs, off, 64);
    }
    if (lane == 0) { wred[wave][0] = lsum; wred[wave][1] = ssum; wred[wave][2] = nobs; }
    __syncthreads();
    if (t == 0) {
        int bid = blockIdx.y * gridDim.x + blockIdx.x;
        part[bid * 3 + 0] = wred[0][0] + wred[1][0] + wred[2][0] + wred[3][0];
        part[bid * 3 + 1] = wred[0][1] + wred[1][1] + wred[2][1] + wred[3][1];
        part[bid * 3 + 2] = wred[0][2] + wred[1][2] + wred[2][2] + wred[3][2];
    }
}

// ---------------------------------------------------------------- k_finalize (reduce 2048 block partials)
__global__ __launch_bounds__(256) void k_finalize(const float* __restrict__ part,
                                                  float* __restrict__ out) {
    __shared__ float sred[3][4];
    int t = threadIdx.x, lane = t & 63, wv = t >> 6;
    float l = 0.f, s = 0.f, n = 0.f;
    for (int i = t; i < 2048; i += 256) {
        l += part[i * 3 + 0];
        s += part[i * 3 + 1];
        n += part[i * 3 + 2];
    }
    #pragma unroll
    for (int off = 32; off; off >>= 1) {
        l += __shfl_down(l, off, 64);
        s += __shfl_down(s, off, 64);
        n += __shfl_down(n, off, 64);
    }
    if (lane == 0) { sred[0][wv] = l; sred[1][wv] = s; sred[2][wv] = n; }
    __syncthreads();
    if (t == 0) {
        float L = sred[0][0] + sred[0][1] + sred[0][2] + sred[0][3];
        float S = sred[1][0] + sred[1][1] + sred[1][2] + sred[1][3];
        float N = fmaxf(sred[2][0] + sred[2][1] + sred[2][2] + sred[2][3], 1.f);
        out[NUV + 0] = L / N;
        out[NUV + 1] = sqrtf(S / N);
    }
}

// ================================================================ launch
extern "C" void kernel_launch(void* const* d_in, const int* in_sizes, int n_in,
                              void* d_out, int out_size, void* d_ws, size_t ws_size,
                              hipStream_t stream) {
    const int* u = (const int*)d_in[0];
    const int* v = (const int*)d_in[1];
    const float* adj    = (const float*)d_in[3];
    const float* u_feat = (const float*)d_in[4];
    const float* v_feat = (const float*)d_in[5];
    const float* u_w    = (const float*)d_in[6];
    const float* v_w    = (const float*)d_in[7];
    const float* Wu1    = (const float*)d_in[8];
    const float* bu1    = (const float*)d_in[9];
    const float* Wv1    = (const float*)d_in[10];
    const float* bv1    = (const float*)d_in[11];
    const float* Wu2    = (const float*)d_in[12];
    const float* Wv2    = (const float*)d_in[13];
    const float* P      = (const float*)d_in[14];
    const float* a      = (const float*)d_in[15];
    float* out = (float*)d_out;

    char* ws = (char*)d_ws;
    // workspace layout (bytes); total ~100 MB.
    // Overlays: codeT on UCAT (dead after k_compact);
    //           codeR on TAU+TBV f16 tables (dead after k_gather2);
    //           part (2048x3 f32 loss partials) on CODE (dead after k_reorder).
    const size_t O_CODE  = 0;                         // 16,777,216 u8
    const size_t O_CNTU  = 16777216;                  // 16,384 i32
    const size_t O_CNTV  = O_CNTU + 16384;            // 16,384 i32
    const size_t O_ACC   = O_CNTV + 16384;            // 256 B (unused in v2)
    const size_t O_TAU   = O_ACC + 256;               // 10,485,760 f16 table (u side)
    const size_t O_TBV   = O_TAU + 10485760;          // 10,485,760 f16 table (v side)
    const size_t O_IDXU  = O_TBV + 10485760;          // 12,582,912 u16 [4096][CAP]
    const size_t O_IDXV  = O_IDXU + 12582912;         // 12,582,912 u16
    const size_t O_NNZU  = O_IDXV + 12582912;         // 16,384 i32
    const size_t O_NNZV  = O_NNZU + 16384;            // 16,384 i32
    const size_t O_RDEG  = O_NNZV + 16384;            // 16,384 f32
    const size_t O_CDEG  = O_RDEG + 16384;            // 16,384 f32
    const size_t O_UNN   = O_CDEG + 16384;            // 4,194,304 f32
    const size_t O_VNN   = O_UNN + 4194304;           // 4,194,304 f32
    const size_t O_UCAT  = O_VNN + 4194304;           // 12,582,912 f32 [4096][768]
    const size_t O_VCAT  = O_UCAT + 12582912;         // 12,582,912 f32
    const size_t O_UH    = O_VCAT + 12582912;         // 2,097,152 f32
    const size_t O_VHB   = O_UH + 2097152;            // 1,048,576 bf16 [4096][128]
    const size_t O_PT    = O_VHB + 1048576;           // 131,072 f32
    const size_t O_TB    = O_PT + 131072;             // 2,097,152 bf16 [2][4096][128]
    const size_t O_CODET = O_UCAT;                    // overlay
    const size_t O_CODER = O_TAU;                     // overlay (fits TAU+TBV)
    const size_t O_PART  = O_CODE;                    // overlay (code dead after k_reorder)

    uint8_t* code  = (uint8_t*)(ws + O_CODE);
    uint8_t* codeT = (uint8_t*)(ws + O_CODET);
    uint8_t* codeR = (uint8_t*)(ws + O_CODER);
    int* cnt_u = (int*)(ws + O_CNTU);
    int* cnt_v = (int*)(ws + O_CNTV);
    unsigned short* T_Au = (unsigned short*)(ws + O_TAU);
    unsigned short* T_Bv = (unsigned short*)(ws + O_TBV);
    unsigned short* idxU = (unsigned short*)(ws + O_IDXU);
    unsigned short* idxV = (unsigned short*)(ws + O_IDXV);
    int* nnzU = (int*)(ws + O_NNZU);
    int* nnzV = (int*)(ws + O_NNZV);
    float* rowDeg = (float*)(ws + O_RDEG);
    float* colDeg = (float*)(ws + O_CDEG);
    float* u_nn = (float*)(ws + O_UNN);
    float* v_nn = (float*)(ws + O_VNN);
    float* ucat = (float*)(ws + O_UCAT);
    float* vcat = (float*)(ws + O_VCAT);
    float* uh = (float*)(ws + O_UH);
    unsigned short* vhb = (unsigned short*)(ws + O_VHB);
    float* Pt = (float*)(ws + O_PT);
    unsigned short* tb = (unsigned short*)(ws + O_TB);
    float* part = (float*)(ws + O_PART);

    hipMemsetAsync(ws + O_CNTU, 0, 16384 + 16384, stream);

    k_counts<<<16, 256, 0, stream>>>(u, v, cnt_u, cnt_v);
    k_code<<<16384, 256, 0, stream>>>(adj, (uchar4*)code);
    k_transpose<<<dim3(64, 64), 256, 0, stream>>>(code, codeT);
    k_wcumsum<<<N4, 256, 0, stream>>>(u_w, cnt_u, T_Au);
    k_wcumsum<<<N4, 256, 0, stream>>>(v_w, cnt_v, T_Bv);
    k_compact<<<N4, 256, 0, stream>>>(code, cnt_v, idxU, nnzU, rowDeg);
    k_compact<<<N4, 256, 0, stream>>>(codeT, cnt_u, idxV, nnzV, colDeg);
    k_gather2<<<N4, 256, 0, stream>>>(idxU, nnzU, T_Bv, u_nn);
    k_gather2<<<N4, 256, 0, stream>>>(idxV, nnzV, T_Au, v_nn);
    // tables now dead -> build codeR over them
    k_reorder<<<N4, 256, 0, stream>>>(code, u, v, codeR);
    k_z<<<N4, 256, 0, stream>>>(u_nn, u, v, colDeg, ucat);
    k_z<<<N4, 256, 0, stream>>>(v_nn, v, u, rowDeg, vcat);
    // u_f = relu(u_features[u] @ Wu1^T + bu1) -> ucat[:, 256:768]
    k_gemm<128, 64, 16, 8, 4, true, true, true, false>
        <<<dim3(32, 8, 1), 256, 0, stream>>>(u_feat, SIDE, u, Wu1, SIDE, bu1,
                                             ucat + H0, HCAT, SIDE, 0, 0);
    k_gemm<128, 64, 16, 8, 4, true, true, true, false>
        <<<dim3(32, 8, 1), 256, 0, stream>>>(v_feat, SIDE, v, Wv1, SIDE, bv1,
                                             vcat + H0, HCAT, SIDE, 0, 0);
    // u_h = relu(ucat @ Wu2^T) -> fp32 (feeds tbuf GEMM)
    k_gemm<64, 32, 16, 4, 2, false, false, true, false>
        <<<dim3(64, 4, 1), 256, 0, stream>>>(ucat, HCAT, nullptr, Wu2, HCAT, nullptr,
                                             uh, H1, HCAT, 0, 0);
    // v_h = relu(vcat @ Wv2^T) -> bf16 directly
    k_gemm<64, 32, 16, 4, 2, false, false, true, true>
        <<<dim3(64, 4, 1), 256, 0, stream>>>(vcat, HCAT, nullptr, Wv2, HCAT, nullptr,
                                             (float*)vhb, H1, HCAT, 0, 0);
    k_Pt<<<128, 256, 0, stream>>>(P, Pt);
    // t[b] = uh @ P[b] -> bf16 directly
    k_gemm<64, 32, 16, 4, 2, false, false, false, true>
        <<<dim3(64, 4, 2), 256, 0, stream>>>(uh, H1, nullptr, Pt, H1, nullptr,
                                             (float*)tb, H1, H1,
                                             (size_t)H1 * H1, (size_t)N4 * H1);
    k_scores3<<<dim3(32, 64), 256, 0, stream>>>(tb, vhb, codeR, a, out, part);
    k_finalize<<<1, 256, 0, stream>>>(part, out);
}

// Round 2
// 1250.492 us; speedup vs baseline: 1.5208x; 1.2888x over previous
//
#include <hip/hip_runtime.h>
#include <stdint.h>

// Problem constants
#define N4   4096
#define H0   256
#define SIDE 1024
#define DIN  512
#define HCAT 768      // H0 + DIN
#define H1   128
#define NC   5
#define NUV  16777216ULL   // 4096*4096
#define CAP  1536          // max compacted entries per row

typedef __attribute__((ext_vector_type(8))) short short8;    // 8 bf16
typedef __attribute__((ext_vector_type(4))) float floatx4;

__device__ __forceinline__ unsigned short f2bf(float f) {
    unsigned int u;
    __builtin_memcpy(&u, &f, 4);
    unsigned int r = (u + 0x7FFFu + ((u >> 16) & 1u)) >> 16;   // RNE
    return (unsigned short)r;
}

// ---------------------------------------------------------------- k_counts
__global__ __launch_bounds__(256) void k_counts(const int* __restrict__ u,
                                                const int* __restrict__ v,
                                                int* __restrict__ cu,
                                                int* __restrict__ cv) {
    int i = blockIdx.x * 256 + threadIdx.x;   // 4096 threads
    atomicAdd(&cu[u[i]], 1);
    atomicAdd(&cv[v[i]], 1);
}

// ---------------------------------------------------------------- k_code
__global__ __launch_bounds__(256) void k_code(const float* __restrict__ adj,
                                              uchar4* __restrict__ code4) {
    size_t g = (size_t)blockIdx.x * 256 + threadIdx.x;
    size_t base = g * 4;
    uchar4 out = {0, 0, 0, 0};
    #pragma unroll
    for (int c = 0; c < NC; c++) {
        float4 s = *(const float4*)(adj + (size_t)c * NUV + base);
        out.x = (s.x != 0.f) ? (unsigned char)(c + 1) : out.x;
        out.y = (s.y != 0.f) ? (unsigned char)(c + 1) : out.y;
        out.z = (s.z != 0.f) ? (unsigned char)(c + 1) : out.z;
        out.w = (s.w != 0.f) ? (unsigned char)(c + 1) : out.w;
    }
    code4[g] = out;
}

// ---------------------------------------------------------------- k_transpose (byte, 64x64 tiles)
__global__ __launch_bounds__(256) void k_transpose(const uint8_t* __restrict__ src,
                                                   uint8_t* __restrict__ dst) {
    __shared__ __align__(16) uint8_t tile[64][80];
    int t = threadIdx.x;
    int row = t >> 2;
    int seg = (t & 3) * 16;
    int p0 = blockIdx.y * 64, q0 = blockIdx.x * 64;
    uint4 vdat = *(const uint4*)(src + (size_t)(p0 + row) * N4 + q0 + seg);
    *(uint4*)(&tile[row][seg]) = vdat;
    __syncthreads();
    union { uint4 u4; uint8_t b[16]; } o;
    #pragma unroll
    for (int l = 0; l < 16; l++) o.b[l] = tile[seg + l][row];
    *(uint4*)(dst + (size_t)(q0 + row) * N4 + p0 + seg) = o.u4;
}

// ---------------------------------------------------------------- k_wcumsum
// out[r][node][h] = f16( cnt[node] * cumsum_r(w)[r][node][h] )
__global__ __launch_bounds__(256) void k_wcumsum(const float* __restrict__ w,
                                                 const int* __restrict__ cnt,
                                                 unsigned short* __restrict__ out) {
    int node = blockIdx.x, h = threadIdx.x;
    float c = (float)cnt[node];
    float acc = 0.f;
    #pragma unroll
    for (int r = 0; r < NC; r++) {
        size_t idx = ((size_t)r * N4 + node) * H0 + h;
        acc += w[idx];
        union { _Float16 h16; unsigned short s; } cvt;
        cvt.h16 = (_Float16)(acc * c);
        out[idx] = cvt.s;
    }
}

// ---------------------------------------------------------------- k_compact
// Compact one code row into entry list (ushort: (r-1)*4096+q), plus
// deg[p] and nnz[p]. Shfl-based scan: 2 barriers total.
__global__ __launch_bounds__(256) void k_compact(const uint8_t* __restrict__ codeRows,
                                                 const int* __restrict__ cntOther,
                                                 unsigned short* __restrict__ idx,
                                                 int* __restrict__ nnz,
                                                 float* __restrict__ deg) {
    __shared__ float cw[4096];
    __shared__ int wtot[4];
    __shared__ float wdeg[4];
    __shared__ unsigned short ebuf[CAP];
    int p = blockIdx.x, t = threadIdx.x;
    int lane = t & 63, wv = t >> 6;
    const int4* co4 = (const int4*)cntOther;
    #pragma unroll
    for (int l = 0; l < 4; l++) {
        int4 ci = co4[t + l * 256];
        ((float4*)cw)[t + l * 256] =
            make_float4((float)ci.x, (float)ci.y, (float)ci.z, (float)ci.w);
    }
    uint4 w = ((const uint4*)(codeRows + (size_t)p * N4))[t];
    unsigned char b[16];
    __builtin_memcpy(b, &w, 16);
    int cnt = 0;
    #pragma unroll
    for (int j = 0; j < 16; j++) cnt += (b[j] != 0);
    // wave-level inclusive scan (no barriers)
    int sc = cnt;
    #pragma unroll
    for (int off = 1; off < 64; off <<= 1) {
        int up = __shfl_up(sc, off, 64);
        if (lane >= off) sc += up;
    }
    if (lane == 63) wtot[wv] = sc;
    __syncthreads();            // covers cw + wtot
    int wbase = 0;
    #pragma unroll
    for (int ww = 0; ww < 4; ww++) wbase += (ww < wv) ? wtot[ww] : 0;
    int total = wtot[0] + wtot[1] + wtot[2] + wtot[3];
    int pos = wbase + sc - cnt;   // block-exclusive prefix
    float dsum = 0.f;
    #pragma unroll
    for (int j = 0; j < 16; j++) {
        int r = b[j];
        if (r) {
            int q = t * 16 + j;
            if (pos < CAP) ebuf[pos] = (unsigned short)((r - 1) * N4 + q);
            pos++;
            dsum += cw[q];
        }
    }
    #pragma unroll
    for (int off = 32; off; off >>= 1) dsum += __shfl_down(dsum, off, 64);
    if (lane == 0) wdeg[wv] = dsum;
    __syncthreads();            // covers ebuf + wdeg
    int tw = total < CAP ? total : CAP;
    if (t == 0) { deg[p] = wdeg[0] + wdeg[1] + wdeg[2] + wdeg[3]; nnz[p] = tw; }
    for (int e = t; e < tw; e += 256) idx[(size_t)p * CAP + e] = ebuf[e];
}

// ---------------------------------------------------------------- k_gather2
// v3: 16B/lane dwordx4 loads (32 lanes cover one 512B table row), 8 entry
// slots in flight per block, inner loop unrolled x4 for MLP (4 independent
// loads per thread in flight). All indices staged in LDS once; 3 barriers.
__global__ __launch_bounds__(256) void k_gather2(const unsigned short* __restrict__ idx,
                                                 const int* __restrict__ nnz,
                                                 const unsigned short* __restrict__ tbl,
                                                 float* __restrict__ outNN) {
    __shared__ unsigned short sidx[CAP];
    __shared__ float red[8][256];   // [slot][h], 8 KB
    int p = blockIdx.x, t = threadIdx.x;
    int n = nnz[p];
    const unsigned short* rowIdx = idx + (size_t)p * CAP;
    for (int i = t; i < n; i += 256) sidx[i] = rowIdx[i];
    __syncthreads();
    int s = t >> 5;        // entry slot 0..7
    int c = t & 31;        // 16B segment within row (covers h = c*8 .. c*8+7)
    const char* tb = (const char*)tbl;
    float acc[8] = {0.f, 0.f, 0.f, 0.f, 0.f, 0.f, 0.f, 0.f};
    int nmain = n & ~31;
    for (int e = s; e < nmain; e += 32) {
        int o0 = ((int)sidx[e])      << 9;
        int o1 = ((int)sidx[e + 8])  << 9;
        int o2 = ((int)sidx[e + 16]) << 9;
        int o3 = ((int)sidx[e + 24]) << 9;
        uint4 d0 = *(const uint4*)(tb + o0 + c * 16);
        uint4 d1 = *(const uint4*)(tb + o1 + c * 16);
        uint4 d2 = *(const uint4*)(tb + o2 + c * 16);
        uint4 d3 = *(const uint4*)(tb + o3 + c * 16);
        union { uint4 u; _Float16 h[8]; } cv;
        cv.u = d0;
        #pragma unroll
        for (int k = 0; k < 8; k++) acc[k] += (float)cv.h[k];
        cv.u = d1;
        #pragma unroll
        for (int k = 0; k < 8; k++) acc[k] += (float)cv.h[k];
        cv.u = d2;
        #pragma unroll
        for (int k = 0; k < 8; k++) acc[k] += (float)cv.h[k];
        cv.u = d3;
        #pragma unroll
        for (int k = 0; k < 8; k++) acc[k] += (float)cv.h[k];
    }
    for (int e = nmain + s; e < n; e += 8) {
        int o = ((int)sidx[e]) << 9;
        uint4 d = *(const uint4*)(tb + o + c * 16);
        union { uint4 u; _Float16 h[8]; } cv;
        cv.u = d;
        #pragma unroll
        for (int k = 0; k < 8; k++) acc[k] += (float)cv.h[k];
    }
    #pragma unroll
    for (int k = 0; k < 8; k++) red[s][c * 8 + k] = acc[k];
    __syncthreads();
    float sum = 0.f;
    #pragma unroll
    for (int ss = 0; ss < 8; ss++) sum += red[ss][t];
    outNN[(size_t)p * H0 + t] = sum;
}

// ---------------------------------------------------------------- k_reorder
// codeR[i][j] = code[u[i]][v[j]]
__global__ __launch_bounds__(256) void k_reorder(const uint8_t* __restrict__ code,
                                                 const int* __restrict__ u,
                                                 const int* __restrict__ v,
                                                 uint8_t* __restrict__ codeR) {
    __shared__ __align__(16) uint8_t rowbuf[4096];
    int i = blockIdx.x, t = threadIdx.x;
    int urow = u[i];
    ((uint4*)rowbuf)[t] = ((const uint4*)(code + (size_t)urow * N4))[t];
    __syncthreads();
    uint8_t ob[16];
    #pragma unroll
    for (int w = 0; w < 4; w++) {
        int4 vv = ((const int4*)v)[t * 4 + w];
        ob[w * 4 + 0] = rowbuf[vv.x];
        ob[w * 4 + 1] = rowbuf[vv.y];
        ob[w * 4 + 2] = rowbuf[vv.z];
        ob[w * 4 + 3] = rowbuf[vv.w];
    }
    uint4 o;
    __builtin_memcpy(&o, ob, 16);
    ((uint4*)(codeR + (size_t)i * N4))[t] = o;
}

// ---------------------------------------------------------------- k_z
__global__ __launch_bounds__(256) void k_z(const float* __restrict__ nn,
                                           const int* __restrict__ idxs,
                                           const int* __restrict__ idxo,
                                           const float* __restrict__ deg,
                                           float* __restrict__ cat) {
    int i = blockIdx.x, h = threadIdx.x;
    float d = deg[idxo[i]];
    float inv = d > 0.f ? 1.f / d : 0.f;
    float val = nn[(size_t)idxs[i] * H0 + h] * inv;
    cat[(size_t)i * HCAT + h] = fmaxf(val, 0.f);
}

// ---------------------------------------------------------------- generic NT GEMM (fp32 in, fp32 or bf16 out)
template <int TM, int TN, int BK, int RM, int RN, bool GATHER, bool BIAS, bool RELU, bool BF16OUT>
__global__ __launch_bounds__(256) void k_gemm(const float* __restrict__ A, int lda,
                                              const int* __restrict__ rowmap,
                                              const float* __restrict__ B, int ldb,
                                              const float* __restrict__ bias,
                                              float* __restrict__ C, int ldc, int K,
                                              size_t bzs, size_t czs) {
    constexpr int TX = TN / RN;
    constexpr int TY = TM / RM;
    static_assert(TX * TY == 256, "block must be 256");
    __shared__ float As[BK][TM + 4];
    __shared__ float Bs[BK][TN + 4];
    int tid = threadIdx.x;
    int tx = tid % TX, ty = tid / TX;
    int i0 = blockIdx.x * TM, n0 = blockIdx.y * TN;
    const float* Bz = B + (size_t)blockIdx.z * bzs;
    float acc[RM][RN] = {};
    for (int k0 = 0; k0 < K; k0 += BK) {
        for (int g = tid; g < TM * BK / 4; g += 256) {
            int i = g / (BK / 4), kc = g % (BK / 4);
            int row = GATHER ? rowmap[i0 + i] : (i0 + i);
            float4 val = *(const float4*)(A + (size_t)row * lda + k0 + kc * 4);
            As[kc * 4 + 0][i] = val.x; As[kc * 4 + 1][i] = val.y;
            As[kc * 4 + 2][i] = val.z; As[kc * 4 + 3][i] = val.w;
        }
        for (int g = tid; g < TN * BK / 4; g += 256) {
            int n = g / (BK / 4), kc = g % (BK / 4);
            float4 val = *(const float4*)(Bz + (size_t)(n0 + n) * ldb + k0 + kc * 4);
            Bs[kc * 4 + 0][n] = val.x; Bs[kc * 4 + 1][n] = val.y;
            Bs[kc * 4 + 2][n] = val.z; Bs[kc * 4 + 3][n] = val.w;
        }
        __syncthreads();
        #pragma unroll
        for (int k = 0; k < BK; k++) {
            float av[RM], bv[RN];
            #pragma unroll
            for (int m = 0; m < RM; m++) av[m] = As[k][ty * RM + m];
            #pragma unroll
            for (int n = 0; n < RN; n++) bv[n] = Bs[k][tx * RN + n];
            #pragma unroll
            for (int m = 0; m < RM; m++)
                #pragma unroll
                for (int n = 0; n < RN; n++)
                    acc[m][n] = fmaf(av[m], bv[n], acc[m][n]);
        }
        __syncthreads();
    }
    #pragma unroll
    for (int m = 0; m < RM; m++) {
        int ig = i0 + ty * RM + m;
        #pragma unroll
        for (int n = 0; n < RN; n++) {
            float vv = acc[m][n];
            if (BIAS) vv += bias[n0 + tx * RN + n];
            if (RELU) vv = fmaxf(vv, 0.f);
            if (BF16OUT) {
                unsigned short* Cz16 = (unsigned short*)C + (size_t)blockIdx.z * czs;
                Cz16[(size_t)ig * ldc + n0 + tx * RN + n] = f2bf(vv);
            } else {
                float* Cz = C + (size_t)blockIdx.z * czs;
                Cz[(size_t)ig * ldc + n0 + tx * RN + n] = vv;
            }
        }
    }
}

// ---------------------------------------------------------------- k_Pt : Pt[b][e][d] = P[b][d][e]
__global__ __launch_bounds__(256) void k_Pt(const float* __restrict__ P, float* __restrict__ Pt) {
    int tid = blockIdx.x * 256 + threadIdx.x;   // 32768
    int b = tid >> 14;
    int d = (tid >> 7) & 127;
    int e = tid & 127;
    Pt[((size_t)b * 128 + e) * 128 + d] = P[tid];
}

// ---------------------------------------------------------------- k_scores3 (MFMA bf16 decoder + softmax epilogue)
// Tile: 64 i x 128 j per block (4 waves, one 16-row strip each). No LDS.
// A frag: tb[b][i0+lr][kc*32+lk*8 ..+8]; B frag: vhb[jb+lr][kc*32+lk*8 ..+8]
// C/D: col=lane&15, row=(lane>>4)*4+reg (m89-verified layout).
// Loss partials: wave shfl-reduce -> LDS -> ONE slot per block in part[].
__global__ __launch_bounds__(256) void k_scores3(const unsigned short* __restrict__ tb,  // [2][4096][128] bf16
                                                 const unsigned short* __restrict__ vhb, // [4096][128] bf16
                                                 const uint8_t* __restrict__ codeR,
                                                 const float* __restrict__ a_f,          // [2][5]
                                                 float* __restrict__ mhat,
                                                 float* __restrict__ part) {
    __shared__ float wred[4][3];
    int t = threadIdx.x;
    int wave = t >> 6, lane = t & 63;
    int lr = lane & 15;          // A row / B col / C col
    int lk = lane >> 4;          // k-subgroup & C row-group
    int i0 = blockIdx.y * 64 + wave * 16;
    int j0 = blockIdx.x * 128;
    float sa0[NC], sa1[NC];
    #pragma unroll
    for (int c = 0; c < NC; c++) { sa0[c] = a_f[c]; sa1[c] = a_f[5 + c]; }

    const unsigned short* t0p = tb;
    const unsigned short* t1p = tb + (size_t)N4 * H1;
    short8 a0[4], a1[4];
    #pragma unroll
    for (int kc = 0; kc < 4; kc++) {
        size_t off = (size_t)(i0 + lr) * H1 + kc * 32 + lk * 8;
        a0[kc] = *(const short8*)(t0p + off);
        a1[kc] = *(const short8*)(t1p + off);
    }

    float lsum = 0.f, ssum = 0.f, nobs = 0.f;
    for (int jt = 0; jt < 8; jt++) {
        int jb = j0 + jt * 16;
        int j = jb + lr;
        // hoist codeR loads above the MFMAs so HBM latency overlaps compute
        const uint8_t* crp = codeR + (size_t)(i0 + lk * 4) * N4 + j;
        int cbv[4];
        cbv[0] = crp[0];
        cbv[1] = crp[N4];
        cbv[2] = crp[2 * N4];
        cbv[3] = crp[3 * N4];
        floatx4 C0 = {0.f, 0.f, 0.f, 0.f}, C1 = {0.f, 0.f, 0.f, 0.f};
        #pragma unroll
        for (int kc = 0; kc < 4; kc++) {
            short8 b = *(const short8*)(vhb + (size_t)(jb + lr) * H1 + kc * 32 + lk * 8);
            C0 = __builtin_amdgcn_mfma_f32_16x16x32_bf16(a0[kc], b, C0, 0, 0, 0);
            C1 = __builtin_amdgcn_mfma_f32_16x16x32_bf16(a1[kc], b, C1, 0, 0, 0);
        }
        #pragma unroll
        for (int r = 0; r < 4; r++) {
            int i = i0 + lk * 4 + r;
            float v0 = C0[r], v1 = C1[r];
            float l[NC];
            float mx = -1e30f;
            #pragma unroll
            for (int c = 0; c < NC; c++) {
                l[c] = sa0[c] * v0 + sa1[c] * v1;
                mx = fmaxf(mx, l[c]);
            }
            float den = 0.f, num = 0.f;
            #pragma unroll
            for (int c = 0; c < NC; c++) {
                float e = __expf(l[c] - mx);
                den += e;
                num += (float)(c + 1) * e;
            }
            float mh = num / den;
            mhat[(size_t)i * N4 + j] = mh;
            int cb = cbv[r];
            if (cb) {
                float lse = mx + __logf(den);
                lsum += lse - l[cb - 1];        // = -logp[cb-1]
                float df = mh - (float)cb;
                ssum += df * df;
                nobs += 1.f;
            }
        }
    }
    #pragma unroll
    for (int off = 32; off; off >>= 1) {
        lsum += __shfl_down(lsum, off, 64);
        ssum += __shfl_down(ssum, off, 64);
        nobs += __shfl_down(nobs, off, 64);
    }
    if (lane == 0) { wred[wave][0] = lsum; wred[wave][1] = ssum; wred[wave][2] = nobs; }
    __syncthreads();
    if (t == 0) {
        int bid = blockIdx.y * gridDim.x + blockIdx.x;
        part[bid * 3 + 0] = wred[0][0] + wred[1][0] + wred[2][0] + wred[3][0];
        part[bid * 3 + 1] = wred[0][1] + wred[1][1] + wred[2][1] + wred[3][1];
        part[bid * 3 + 2] = wred[0][2] + wred[1][2] + wred[2][2] + wred[3][2];
    }
}

// ---------------------------------------------------------------- k_finalize (reduce 2048 block partials)
__global__ __launch_bounds__(256) void k_finalize(const float* __restrict__ part,
                                                  float* __restrict__ out) {
    __shared__ float sred[3][4];
    int t = threadIdx.x, lane = t & 63, wv = t >> 6;
    float l = 0.f, s = 0.f, n = 0.f;
    for (int i = t; i < 2048; i += 256) {
        l += part[i * 3 + 0];
        s += part[i * 3 + 1];
        n += part[i * 3 + 2];
    }
    #pragma unroll
    for (int off = 32; off; off >>= 1) {
        l += __shfl_down(l, off, 64);
        s += __shfl_down(s, off, 64);
        n += __shfl_down(n, off, 64);
    }
    if (lane == 0) { sred[0][wv] = l; sred[1][wv] = s; sred[2][wv] = n; }
    __syncthreads();
    if (t == 0) {
        float L = sred[0][0] + sred[0][1] + sred[0][2] + sred[0][3];
        float S = sred[1][0] + sred[1][1] + sred[1][2] + sred[1][3];
        float N = fmaxf(sred[2][0] + sred[2][1] + sred[2][2] + sred[2][3], 1.f);
        out[NUV + 0] = L / N;
        out[NUV + 1] = sqrtf(S / N);
    }
}

// ================================================================ launch
extern "C" void kernel_launch(void* const* d_in, const int* in_sizes, int n_in,
                              void* d_out, int out_size, void* d_ws, size_t ws_size,
                              hipStream_t stream) {
    const int* u = (const int*)d_in[0];
    const int* v = (const int*)d_in[1];
    const float* adj    = (const float*)d_in[3];
    const float* u_feat = (const float*)d_in[4];
    const float* v_feat = (const float*)d_in[5];
    const float* u_w    = (const float*)d_in[6];
    const float* v_w    = (const float*)d_in[7];
    const float* Wu1    = (const float*)d_in[8];
    const float* bu1    = (const float*)d_in[9];
    const float* Wv1    = (const float*)d_in[10];
    const float* bv1    = (const float*)d_in[11];
    const float* Wu2    = (const float*)d_in[12];
    const float* Wv2    = (const float*)d_in[13];
    const float* P      = (const float*)d_in[14];
    const float* a      = (const float*)d_in[15];
    float* out = (float*)d_out;

    char* ws = (char*)d_ws;
    // workspace layout (bytes); total ~100 MB.
    // Overlays: codeT on UCAT (dead after k_compact);
    //           codeR on TAU+TBV f16 tables (dead after k_gather2);
    //           part (2048x3 f32 loss partials) on CODE (dead after k_reorder).
    const size_t O_CODE  = 0;                         // 16,777,216 u8
    const size_t O_CNTU  = 16777216;                  // 16,384 i32
    const size_t O_CNTV  = O_CNTU + 16384;            // 16,384 i32
    const size_t O_ACC   = O_CNTV + 16384;            // 256 B (unused)
    const size_t O_TAU   = O_ACC + 256;               // 10,485,760 f16 table (u side)
    const size_t O_TBV   = O_TAU + 10485760;          // 10,485,760 f16 table (v side)
    const size_t O_IDXU  = O_TBV + 10485760;          // 12,582,912 u16 [4096][CAP]
    const size_t O_IDXV  = O_IDXU + 12582912;         // 12,582,912 u16
    const size_t O_NNZU  = O_IDXV + 12582912;         // 16,384 i32
    const size_t O_NNZV  = O_NNZU + 16384;            // 16,384 i32
    const size_t O_RDEG  = O_NNZV + 16384;            // 16,384 f32
    const size_t O_CDEG  = O_RDEG + 16384;            // 16,384 f32
    const size_t O_UNN   = O_CDEG + 16384;            // 4,194,304 f32
    const size_t O_VNN   = O_UNN + 4194304;           // 4,194,304 f32
    const size_t O_UCAT  = O_VNN + 4194304;           // 12,582,912 f32 [4096][768]
    const size_t O_VCAT  = O_UCAT + 12582912;         // 12,582,912 f32
    const size_t O_UH    = O_VCAT + 12582912;         // 2,097,152 f32
    const size_t O_VHB   = O_UH + 2097152;            // 1,048,576 bf16 [4096][128]
    const size_t O_PT    = O_VHB + 1048576;           // 131,072 f32
    const size_t O_TB    = O_PT + 131072;             // 2,097,152 bf16 [2][4096][128]
    const size_t O_CODET = O_UCAT;                    // overlay
    const size_t O_CODER = O_TAU;                     // overlay (fits TAU+TBV)
    const size_t O_PART  = O_CODE;                    // overlay (code dead after k_reorder)

    uint8_t* code  = (uint8_t*)(ws + O_CODE);
    uint8_t* codeT = (uint8_t*)(ws + O_CODET);
    uint8_t* codeR = (uint8_t*)(ws + O_CODER);
    int* cnt_u = (int*)(ws + O_CNTU);
    int* cnt_v = (int*)(ws + O_CNTV);
    unsigned short* T_Au = (unsigned short*)(ws + O_TAU);
    unsigned short* T_Bv = (unsigned short*)(ws + O_TBV);
    unsigned short* idxU = (unsigned short*)(ws + O_IDXU);
    unsigned short* idxV = (unsigned short*)(ws + O_IDXV);
    int* nnzU = (int*)(ws + O_NNZU);
    int* nnzV = (int*)(ws + O_NNZV);
    float* rowDeg = (float*)(ws + O_RDEG);
    float* colDeg = (float*)(ws + O_CDEG);
    float* u_nn = (float*)(ws + O_UNN);
    float* v_nn = (float*)(ws + O_VNN);
    float* ucat = (float*)(ws + O_UCAT);
    float* vcat = (float*)(ws + O_VCAT);
    float* uh = (float*)(ws + O_UH);
    unsigned short* vhb = (unsigned short*)(ws + O_VHB);
    float* Pt = (float*)(ws + O_PT);
    unsigned short* tb = (unsigned short*)(ws + O_TB);
    float* part = (float*)(ws + O_PART);

    hipMemsetAsync(ws + O_CNTU, 0, 16384 + 16384, stream);

    k_counts<<<16, 256, 0, stream>>>(u, v, cnt_u, cnt_v);
    k_code<<<16384, 256, 0, stream>>>(adj, (uchar4*)code);
    k_transpose<<<dim3(64, 64), 256, 0, stream>>>(code, codeT);
    k_wcumsum<<<N4, 256, 0, stream>>>(u_w, cnt_u, T_Au);
    k_wcumsum<<<N4, 256, 0, stream>>>(v_w, cnt_v, T_Bv);
    k_compact<<<N4, 256, 0, stream>>>(code, cnt_v, idxU, nnzU, rowDeg);
    k_compact<<<N4, 256, 0, stream>>>(codeT, cnt_u, idxV, nnzV, colDeg);
    k_gather2<<<N4, 256, 0, stream>>>(idxU, nnzU, T_Bv, u_nn);
    k_gather2<<<N4, 256, 0, stream>>>(idxV, nnzV, T_Au, v_nn);
    // tables now dead -> build codeR over them
    k_reorder<<<N4, 256, 0, stream>>>(code, u, v, codeR);
    k_z<<<N4, 256, 0, stream>>>(u_nn, u, v, colDeg, ucat);
    k_z<<<N4, 256, 0, stream>>>(v_nn, v, u, rowDeg, vcat);
    // u_f = relu(u_features[u] @ Wu1^T + bu1) -> ucat[:, 256:768]
    k_gemm<128, 64, 16, 8, 4, true, true, true, false>
        <<<dim3(32, 8, 1), 256, 0, stream>>>(u_feat, SIDE, u, Wu1, SIDE, bu1,
                                             ucat + H0, HCAT, SIDE, 0, 0);
    k_gemm<128, 64, 16, 8, 4, true, true, true, false>
        <<<dim3(32, 8, 1), 256, 0, stream>>>(v_feat, SIDE, v, Wv1, SIDE, bv1,
                                             vcat + H0, HCAT, SIDE, 0, 0);
    // u_h = relu(ucat @ Wu2^T) -> fp32 (feeds tbuf GEMM)
    k_gemm<64, 32, 16, 4, 2, false, false, true, false>
        <<<dim3(64, 4, 1), 256, 0, stream>>>(ucat, HCAT, nullptr, Wu2, HCAT, nullptr,
                                             uh, H1, HCAT, 0, 0);
    // v_h = relu(vcat @ Wv2^T) -> bf16 directly
    k_gemm<64, 32, 16, 4, 2, false, false, true, true>
        <<<dim3(64, 4, 1), 256, 0, stream>>>(vcat, HCAT, nullptr, Wv2, HCAT, nullptr,
                                             (float*)vhb, H1, HCAT, 0, 0);
    k_Pt<<<128, 256, 0, stream>>>(P, Pt);
    // t[b] = uh @ P[b] -> bf16 directly
    k_gemm<64, 32, 16, 4, 2, false, false, false, true>
        <<<dim3(64, 4, 2), 256, 0, stream>>>(uh, H1, nullptr, Pt, H1, nullptr,
                                             (float*)tb, H1, H1,
                                             (size_t)H1 * H1, (size_t)N4 * H1);
    k_scores3<<<dim3(32, 64), 256, 0, stream>>>(tb, vhb, codeR, a, out, part);
    k_finalize<<<1, 256, 0, stream>>>(part, out);
}

// Round 3
// 1169.518 us; speedup vs baseline: 1.6261x; 1.0692x over previous
//
#include <hip/hip_runtime.h>
#include <stdint.h>

// Problem constants
#define N4   4096
#define H0   256
#define SIDE 1024
#define DIN  512
#define HCAT 768      // H0 + DIN
#define H1   128
#define NC   5
#define NUV  16777216ULL   // 4096*4096
#define CAP  1536          // max compacted entries per row

typedef __attribute__((ext_vector_type(8))) short short8;    // 8 bf16
typedef __attribute__((ext_vector_type(4))) float floatx4;

__device__ __forceinline__ unsigned short f2bf(float f) {
    unsigned int u;
    __builtin_memcpy(&u, &f, 4);
    unsigned int r = (u + 0x7FFFu + ((u >> 16) & 1u)) >> 16;   // RNE
    return (unsigned short)r;
}

// ---------------------------------------------------------------- k_counts
__global__ __launch_bounds__(256) void k_counts(const int* __restrict__ u,
                                                const int* __restrict__ v,
                                                int* __restrict__ cu,
                                                int* __restrict__ cv) {
    int i = blockIdx.x * 256 + threadIdx.x;   // 4096 threads
    atomicAdd(&cu[u[i]], 1);
    atomicAdd(&cv[v[i]], 1);
}

// ---------------------------------------------------------------- k_code
__global__ __launch_bounds__(256) void k_code(const float* __restrict__ adj,
                                              uchar4* __restrict__ code4) {
    size_t g = (size_t)blockIdx.x * 256 + threadIdx.x;
    size_t base = g * 4;
    uchar4 out = {0, 0, 0, 0};
    #pragma unroll
    for (int c = 0; c < NC; c++) {
        float4 s = *(const float4*)(adj + (size_t)c * NUV + base);
        out.x = (s.x != 0.f) ? (unsigned char)(c + 1) : out.x;
        out.y = (s.y != 0.f) ? (unsigned char)(c + 1) : out.y;
        out.z = (s.z != 0.f) ? (unsigned char)(c + 1) : out.z;
        out.w = (s.w != 0.f) ? (unsigned char)(c + 1) : out.w;
    }
    code4[g] = out;
}

// ---------------------------------------------------------------- k_transpose (byte, 64x64 tiles)
__global__ __launch_bounds__(256) void k_transpose(const uint8_t* __restrict__ src,
                                                   uint8_t* __restrict__ dst) {
    __shared__ __align__(16) uint8_t tile[64][80];
    int t = threadIdx.x;
    int row = t >> 2;
    int seg = (t & 3) * 16;
    int p0 = blockIdx.y * 64, q0 = blockIdx.x * 64;
    uint4 vdat = *(const uint4*)(src + (size_t)(p0 + row) * N4 + q0 + seg);
    *(uint4*)(&tile[row][seg]) = vdat;
    __syncthreads();
    union { uint4 u4; uint8_t b[16]; } o;
    #pragma unroll
    for (int l = 0; l < 16; l++) o.b[l] = tile[seg + l][row];
    *(uint4*)(dst + (size_t)(q0 + row) * N4 + p0 + seg) = o.u4;
}

// ---------------------------------------------------------------- k_wcumsum
// out[r][node][h] = f16( cnt[node] * cumsum_r(w)[r][node][h] )
__global__ __launch_bounds__(256) void k_wcumsum(const float* __restrict__ w,
                                                 const int* __restrict__ cnt,
                                                 unsigned short* __restrict__ out) {
    int node = blockIdx.x, h = threadIdx.x;
    float c = (float)cnt[node];
    float acc = 0.f;
    #pragma unroll
    for (int r = 0; r < NC; r++) {
        size_t idx = ((size_t)r * N4 + node) * H0 + h;
        acc += w[idx];
        union { _Float16 h16; unsigned short s; } cvt;
        cvt.h16 = (_Float16)(acc * c);
        out[idx] = cvt.s;
    }
}

// ---------------------------------------------------------------- k_compact
__global__ __launch_bounds__(256) void k_compact(const uint8_t* __restrict__ codeRows,
                                                 const int* __restrict__ cntOther,
                                                 unsigned short* __restrict__ idx,
                                                 int* __restrict__ nnz,
                                                 float* __restrict__ deg) {
    __shared__ float cw[4096];
    __shared__ int wtot[4];
    __shared__ float wdeg[4];
    __shared__ unsigned short ebuf[CAP];
    int p = blockIdx.x, t = threadIdx.x;
    int lane = t & 63, wv = t >> 6;
    const int4* co4 = (const int4*)cntOther;
    #pragma unroll
    for (int l = 0; l < 4; l++) {
        int4 ci = co4[t + l * 256];
        ((float4*)cw)[t + l * 256] =
            make_float4((float)ci.x, (float)ci.y, (float)ci.z, (float)ci.w);
    }
    uint4 w = ((const uint4*)(codeRows + (size_t)p * N4))[t];
    unsigned char b[16];
    __builtin_memcpy(b, &w, 16);
    int cnt = 0;
    #pragma unroll
    for (int j = 0; j < 16; j++) cnt += (b[j] != 0);
    int sc = cnt;
    #pragma unroll
    for (int off = 1; off < 64; off <<= 1) {
        int up = __shfl_up(sc, off, 64);
        if (lane >= off) sc += up;
    }
    if (lane == 63) wtot[wv] = sc;
    __syncthreads();            // covers cw + wtot
    int wbase = 0;
    #pragma unroll
    for (int ww = 0; ww < 4; ww++) wbase += (ww < wv) ? wtot[ww] : 0;
    int total = wtot[0] + wtot[1] + wtot[2] + wtot[3];
    int pos = wbase + sc - cnt;   // block-exclusive prefix
    float dsum = 0.f;
    #pragma unroll
    for (int j = 0; j < 16; j++) {
        int r = b[j];
        if (r) {
            int q = t * 16 + j;
            if (pos < CAP) ebuf[pos] = (unsigned short)((r - 1) * N4 + q);
            pos++;
            dsum += cw[q];
        }
    }
    #pragma unroll
    for (int off = 32; off; off >>= 1) dsum += __shfl_down(dsum, off, 64);
    if (lane == 0) wdeg[wv] = dsum;
    __syncthreads();            // covers ebuf + wdeg
    int tw = total < CAP ? total : CAP;
    if (t == 0) { deg[p] = wdeg[0] + wdeg[1] + wdeg[2] + wdeg[3]; nnz[p] = tw; }
    for (int e = t; e < tw; e += 256) idx[(size_t)p * CAP + e] = ebuf[e];
}

// ---------------------------------------------------------------- k_gather2
// v3: 16B/lane dwordx4 loads (32 lanes cover one 512B table row), 8 entry
// slots in flight per block, inner loop unrolled x4 for MLP.
__global__ __launch_bounds__(256) void k_gather2(const unsigned short* __restrict__ idx,
                                                 const int* __restrict__ nnz,
                                                 const unsigned short* __restrict__ tbl,
                                                 float* __restrict__ outNN) {
    __shared__ unsigned short sidx[CAP];
    __shared__ float red[8][256];   // [slot][h], 8 KB
    int p = blockIdx.x, t = threadIdx.x;
    int n = nnz[p];
    const unsigned short* rowIdx = idx + (size_t)p * CAP;
    for (int i = t; i < n; i += 256) sidx[i] = rowIdx[i];
    __syncthreads();
    int s = t >> 5;        // entry slot 0..7
    int c = t & 31;        // 16B segment within row
    const char* tb = (const char*)tbl;
    float acc[8] = {0.f, 0.f, 0.f, 0.f, 0.f, 0.f, 0.f, 0.f};
    int nmain = n & ~31;
    for (int e = s; e < nmain; e += 32) {
        int o0 = ((int)sidx[e])      << 9;
        int o1 = ((int)sidx[e + 8])  << 9;
        int o2 = ((int)sidx[e + 16]) << 9;
        int o3 = ((int)sidx[e + 24]) << 9;
        uint4 d0 = *(const uint4*)(tb + o0 + c * 16);
        uint4 d1 = *(const uint4*)(tb + o1 + c * 16);
        uint4 d2 = *(const uint4*)(tb + o2 + c * 16);
        uint4 d3 = *(const uint4*)(tb + o3 + c * 16);
        union { uint4 u; _Float16 h[8]; } cv;
        cv.u = d0;
        #pragma unroll
        for (int k = 0; k < 8; k++) acc[k] += (float)cv.h[k];
        cv.u = d1;
        #pragma unroll
        for (int k = 0; k < 8; k++) acc[k] += (float)cv.h[k];
        cv.u = d2;
        #pragma unroll
        for (int k = 0; k < 8; k++) acc[k] += (float)cv.h[k];
        cv.u = d3;
        #pragma unroll
        for (int k = 0; k < 8; k++) acc[k] += (float)cv.h[k];
    }
    for (int e = nmain + s; e < n; e += 8) {
        int o = ((int)sidx[e]) << 9;
        uint4 d = *(const uint4*)(tb + o + c * 16);
        union { uint4 u; _Float16 h[8]; } cv;
        cv.u = d;
        #pragma unroll
        for (int k = 0; k < 8; k++) acc[k] += (float)cv.h[k];
    }
    #pragma unroll
    for (int k = 0; k < 8; k++) red[s][c * 8 + k] = acc[k];
    __syncthreads();
    float sum = 0.f;
    #pragma unroll
    for (int ss = 0; ss < 8; ss++) sum += red[ss][t];
    outNN[(size_t)p * H0 + t] = sum;
}

// ---------------------------------------------------------------- k_reorder
// codeR[i][j] = code[u[i]][v[j]]
__global__ __launch_bounds__(256) void k_reorder(const uint8_t* __restrict__ code,
                                                 const int* __restrict__ u,
                                                 const int* __restrict__ v,
                                                 uint8_t* __restrict__ codeR) {
    __shared__ __align__(16) uint8_t rowbuf[4096];
    int i = blockIdx.x, t = threadIdx.x;
    int urow = u[i];
    ((uint4*)rowbuf)[t] = ((const uint4*)(code + (size_t)urow * N4))[t];
    __syncthreads();
    uint8_t ob[16];
    #pragma unroll
    for (int w = 0; w < 4; w++) {
        int4 vv = ((const int4*)v)[t * 4 + w];
        ob[w * 4 + 0] = rowbuf[vv.x];
        ob[w * 4 + 1] = rowbuf[vv.y];
        ob[w * 4 + 2] = rowbuf[vv.z];
        ob[w * 4 + 3] = rowbuf[vv.w];
    }
    uint4 o;
    __builtin_memcpy(&o, ob, 16);
    ((uint4*)(codeR + (size_t)i * N4))[t] = o;
}

// ---------------------------------------------------------------- k_z
__global__ __launch_bounds__(256) void k_z(const float* __restrict__ nn,
                                           const int* __restrict__ idxs,
                                           const int* __restrict__ idxo,
                                           const float* __restrict__ deg,
                                           float* __restrict__ cat) {
    int i = blockIdx.x, h = threadIdx.x;
    float d = deg[idxo[i]];
    float inv = d > 0.f ? 1.f / d : 0.f;
    float val = nn[(size_t)idxs[i] * H0 + h] * inv;
    cat[(size_t)i * HCAT + h] = fmaxf(val, 0.f);
}

// ---------------------------------------------------------------- k_split (fp32 -> bf16 hi + lo)
__global__ __launch_bounds__(256) void k_split(const float* __restrict__ src,
                                               unsigned short* __restrict__ hi,
                                               unsigned short* __restrict__ lo) {
    size_t g = ((size_t)blockIdx.x * 256 + threadIdx.x) * 4;
    float4 x = *(const float4*)(src + g);
    float f[4] = {x.x, x.y, x.z, x.w};
    ushort4 h4, l4;
    unsigned short hh[4], ll[4];
    #pragma unroll
    for (int k = 0; k < 4; k++) {
        unsigned short hb = f2bf(f[k]);
        unsigned int hu = (unsigned int)hb << 16;
        float hf; __builtin_memcpy(&hf, &hu, 4);
        hh[k] = hb;
        ll[k] = f2bf(f[k] - hf);
    }
    h4 = make_ushort4(hh[0], hh[1], hh[2], hh[3]);
    l4 = make_ushort4(ll[0], ll[1], ll[2], ll[3]);
    *(ushort4*)(hi + g) = h4;
    *(ushort4*)(lo + g) = l4;
}

// ---------------------------------------------------------------- k_l1gemm (MFMA bf16 split GEMM, layer 1)
// C[rowmap[i]][n] = relu( sum_k A[rowmap[i]][k]*B[n][k] + bias[n] ), K=1024.
// A,B given as bf16 hi/lo pairs; product = Ah*Bh + Ah*Bl + Al*Bh (~fp32 acc).
// Tile: 64 i x 64 n per block (4 waves x 16-row strips). Same verified
// fragment mapping as k_scores3: A row / B col = lane&15 on load;
// D row = (lane>>4)*4 + reg, D col = lane&15.
__global__ __launch_bounds__(256) void k_l1gemm(const unsigned short* __restrict__ Ahi,
                                                const unsigned short* __restrict__ Alo,
                                                const int* __restrict__ rowmap,
                                                const unsigned short* __restrict__ Bhi,
                                                const unsigned short* __restrict__ Blo,
                                                const float* __restrict__ bias,
                                                float* __restrict__ C) {
    int t = threadIdx.x;
    int wave = t >> 6, lane = t & 63;
    int lr = lane & 15;
    int lk = lane >> 4;
    int i0 = blockIdx.y * 64 + wave * 16;
    int n0 = blockIdx.x * 64;
    int gi = rowmap[i0 + lr];
    const unsigned short* pah = Ahi + (size_t)gi * SIDE + lk * 8;
    const unsigned short* pal = Alo + (size_t)gi * SIDE + lk * 8;
    floatx4 acc[4];
    #pragma unroll
    for (int jt = 0; jt < 4; jt++) acc[jt] = (floatx4){0.f, 0.f, 0.f, 0.f};
    for (int kc = 0; kc < SIDE / 32; kc++) {
        short8 ah = *(const short8*)(pah + kc * 32);
        short8 al = *(const short8*)(pal + kc * 32);
        #pragma unroll
        for (int jt = 0; jt < 4; jt++) {
            int bc = n0 + jt * 16 + lr;
            const unsigned short* pb = Bhi + (size_t)bc * SIDE + kc * 32 + lk * 8;
            const unsigned short* pbl = Blo + (size_t)bc * SIDE + kc * 32 + lk * 8;
            short8 bh = *(const short8*)pb;
            short8 bl = *(const short8*)pbl;
            acc[jt] = __builtin_amdgcn_mfma_f32_16x16x32_bf16(ah, bh, acc[jt], 0, 0, 0);
            acc[jt] = __builtin_amdgcn_mfma_f32_16x16x32_bf16(ah, bl, acc[jt], 0, 0, 0);
            acc[jt] = __builtin_amdgcn_mfma_f32_16x16x32_bf16(al, bh, acc[jt], 0, 0, 0);
        }
    }
    #pragma unroll
    for (int jt = 0; jt < 4; jt++) {
        int cn = n0 + jt * 16 + lr;
        float b = bias[cn];
        #pragma unroll
        for (int r = 0; r < 4; r++) {
            int ci = i0 + lk * 4 + r;
            C[(size_t)ci * HCAT + cn] = fmaxf(acc[jt][r] + b, 0.f);
        }
    }
}

// ---------------------------------------------------------------- generic NT GEMM (fp32 in, fp32 or bf16 out)
template <int TM, int TN, int BK, int RM, int RN, bool GATHER, bool BIAS, bool RELU, bool BF16OUT>
__global__ __launch_bounds__(256) void k_gemm(const float* __restrict__ A, int lda,
                                              const int* __restrict__ rowmap,
                                              const float* __restrict__ B, int ldb,
                                              const float* __restrict__ bias,
                                              float* __restrict__ C, int ldc, int K,
                                              size_t bzs, size_t czs) {
    constexpr int TX = TN / RN;
    constexpr int TY = TM / RM;
    static_assert(TX * TY == 256, "block must be 256");
    __shared__ float As[BK][TM + 4];
    __shared__ float Bs[BK][TN + 4];
    int tid = threadIdx.x;
    int tx = tid % TX, ty = tid / TX;
    int i0 = blockIdx.x * TM, n0 = blockIdx.y * TN;
    const float* Bz = B + (size_t)blockIdx.z * bzs;
    float acc[RM][RN] = {};
    for (int k0 = 0; k0 < K; k0 += BK) {
        for (int g = tid; g < TM * BK / 4; g += 256) {
            int i = g / (BK / 4), kc = g % (BK / 4);
            int row = GATHER ? rowmap[i0 + i] : (i0 + i);
            float4 val = *(const float4*)(A + (size_t)row * lda + k0 + kc * 4);
            As[kc * 4 + 0][i] = val.x; As[kc * 4 + 1][i] = val.y;
            As[kc * 4 + 2][i] = val.z; As[kc * 4 + 3][i] = val.w;
        }
        for (int g = tid; g < TN * BK / 4; g += 256) {
            int n = g / (BK / 4), kc = g % (BK / 4);
            float4 val = *(const float4*)(Bz + (size_t)(n0 + n) * ldb + k0 + kc * 4);
            Bs[kc * 4 + 0][n] = val.x; Bs[kc * 4 + 1][n] = val.y;
            Bs[kc * 4 + 2][n] = val.z; Bs[kc * 4 + 3][n] = val.w;
        }
        __syncthreads();
        #pragma unroll
        for (int k = 0; k < BK; k++) {
            float av[RM], bv[RN];
            #pragma unroll
            for (int m = 0; m < RM; m++) av[m] = As[k][ty * RM + m];
            #pragma unroll
            for (int n = 0; n < RN; n++) bv[n] = Bs[k][tx * RN + n];
            #pragma unroll
            for (int m = 0; m < RM; m++)
                #pragma unroll
                for (int n = 0; n < RN; n++)
                    acc[m][n] = fmaf(av[m], bv[n], acc[m][n]);
        }
        __syncthreads();
    }
    #pragma unroll
    for (int m = 0; m < RM; m++) {
        int ig = i0 + ty * RM + m;
        #pragma unroll
        for (int n = 0; n < RN; n++) {
            float vv = acc[m][n];
            if (BIAS) vv += bias[n0 + tx * RN + n];
            if (RELU) vv = fmaxf(vv, 0.f);
            if (BF16OUT) {
                unsigned short* Cz16 = (unsigned short*)C + (size_t)blockIdx.z * czs;
                Cz16[(size_t)ig * ldc + n0 + tx * RN + n] = f2bf(vv);
            } else {
                float* Cz = C + (size_t)blockIdx.z * czs;
                Cz[(size_t)ig * ldc + n0 + tx * RN + n] = vv;
            }
        }
    }
}

// ---------------------------------------------------------------- k_Pt : Pt[b][e][d] = P[b][d][e]
__global__ __launch_bounds__(256) void k_Pt(const float* __restrict__ P, float* __restrict__ Pt) {
    int tid = blockIdx.x * 256 + threadIdx.x;   // 32768
    int b = tid >> 14;
    int d = (tid >> 7) & 127;
    int e = tid & 127;
    Pt[((size_t)b * 128 + e) * 128 + d] = P[tid];
}

// ---------------------------------------------------------------- k_scores3 (MFMA bf16 decoder + softmax epilogue)
__global__ __launch_bounds__(256) void k_scores3(const unsigned short* __restrict__ tb,  // [2][4096][128] bf16
                                                 const unsigned short* __restrict__ vhb, // [4096][128] bf16
                                                 const uint8_t* __restrict__ codeR,
                                                 const float* __restrict__ a_f,          // [2][5]
                                                 float* __restrict__ mhat,
                                                 float* __restrict__ part) {
    __shared__ float wred[4][3];
    int t = threadIdx.x;
    int wave = t >> 6, lane = t & 63;
    int lr = lane & 15;          // A row / B col / C col
    int lk = lane >> 4;          // k-subgroup & C row-group
    int i0 = blockIdx.y * 64 + wave * 16;
    int j0 = blockIdx.x * 128;
    float sa0[NC], sa1[NC];
    #pragma unroll
    for (int c = 0; c < NC; c++) { sa0[c] = a_f[c]; sa1[c] = a_f[5 + c]; }

    const unsigned short* t0p = tb;
    const unsigned short* t1p = tb + (size_t)N4 * H1;
    short8 a0[4], a1[4];
    #pragma unroll
    for (int kc = 0; kc < 4; kc++) {
        size_t off = (size_t)(i0 + lr) * H1 + kc * 32 + lk * 8;
        a0[kc] = *(const short8*)(t0p + off);
        a1[kc] = *(const short8*)(t1p + off);
    }

    float lsum = 0.f, ssum = 0.f, nobs = 0.f;
    for (int jt = 0; jt < 8; jt++) {
        int jb = j0 + jt * 16;
        int j = jb + lr;
        // hoist codeR loads above the MFMAs so HBM latency overlaps compute
        const uint8_t* crp = codeR + (size_t)(i0 + lk * 4) * N4 + j;
        int cbv[4];
        cbv[0] = crp[0];
        cbv[1] = crp[N4];
        cbv[2] = crp[2 * N4];
        cbv[3] = crp[3 * N4];
        floatx4 C0 = {0.f, 0.f, 0.f, 0.f}, C1 = {0.f, 0.f, 0.f, 0.f};
        #pragma unroll
        for (int kc = 0; kc < 4; kc++) {
            short8 b = *(const short8*)(vhb + (size_t)(jb + lr) * H1 + kc * 32 + lk * 8);
            C0 = __builtin_amdgcn_mfma_f32_16x16x32_bf16(a0[kc], b, C0, 0, 0, 0);
            C1 = __builtin_amdgcn_mfma_f32_16x16x32_bf16(a1[kc], b, C1, 0, 0, 0);
        }
        #pragma unroll
        for (int r = 0; r < 4; r++) {
            int i = i0 + lk * 4 + r;
            float v0 = C0[r], v1 = C1[r];
            float l[NC];
            float mx = -1e30f;
            #pragma unroll
            for (int c = 0; c < NC; c++) {
                l[c] = sa0[c] * v0 + sa1[c] * v1;
                mx = fmaxf(mx, l[c]);
            }
            float den = 0.f, num = 0.f;
            #pragma unroll
            for (int c = 0; c < NC; c++) {
                float e = __expf(l[c] - mx);
                den += e;
                num += (float)(c + 1) * e;
            }
            float mh = num / den;
            mhat[(size_t)i * N4 + j] = mh;
            int cb = cbv[r];
            if (cb) {
                float lse = mx + __logf(den);
                lsum += lse - l[cb - 1];        // = -logp[cb-1]
                float df = mh - (float)cb;
                ssum += df * df;
                nobs += 1.f;
            }
        }
    }
    #pragma unroll
    for (int off = 32; off; off >>= 1) {
        lsum += __shfl_down(lsum, off, 64);
        ssum += __shfl_down(ssum, off, 64);
        nobs += __shfl_down(nobs, off, 64);
    }
    if (lane == 0) { wred[wave][0] = lsum; wred[wave][1] = ssum; wred[wave][2] = nobs; }
    __syncthreads();
    if (t == 0) {
        int bid = blockIdx.y * gridDim.x + blockIdx.x;
        part[bid * 3 + 0] = wred[0][0] + wred[1][0] + wred[2][0] + wred[3][0];
        part[bid * 3 + 1] = wred[0][1] + wred[1][1] + wred[2][1] + wred[3][1];
        part[bid * 3 + 2] = wred[0][2] + wred[1][2] + wred[2][2] + wred[3][2];
    }
}

// ---------------------------------------------------------------- k_finalize (reduce 2048 block partials)
__global__ __launch_bounds__(256) void k_finalize(const float* __restrict__ part,
                                                  float* __restrict__ out) {
    __shared__ float sred[3][4];
    int t = threadIdx.x, lane = t & 63, wv = t >> 6;
    float l = 0.f, s = 0.f, n = 0.f;
    for (int i = t; i < 2048; i += 256) {
        l += part[i * 3 + 0];
        s += part[i * 3 + 1];
        n += part[i * 3 + 2];
    }
    #pragma unroll
    for (int off = 32; off; off >>= 1) {
        l += __shfl_down(l, off, 64);
        s += __shfl_down(s, off, 64);
        n += __shfl_down(n, off, 64);
    }
    if (lane == 0) { sred[0][wv] = l; sred[1][wv] = s; sred[2][wv] = n; }
    __syncthreads();
    if (t == 0) {
        float L = sred[0][0] + sred[0][1] + sred[0][2] + sred[0][3];
        float S = sred[1][0] + sred[1][1] + sred[1][2] + sred[1][3];
        float N = fmaxf(sred[2][0] + sred[2][1] + sred[2][2] + sred[2][3], 1.f);
        out[NUV + 0] = L / N;
        out[NUV + 1] = sqrtf(S / N);
    }
}

// ================================================================ launch
extern "C" void kernel_launch(void* const* d_in, const int* in_sizes, int n_in,
                              void* d_out, int out_size, void* d_ws, size_t ws_size,
                              hipStream_t stream) {
    const int* u = (const int*)d_in[0];
    const int* v = (const int*)d_in[1];
    const float* adj    = (const float*)d_in[3];
    const float* u_feat = (const float*)d_in[4];
    const float* v_feat = (const float*)d_in[5];
    const float* u_w    = (const float*)d_in[6];
    const float* v_w    = (const float*)d_in[7];
    const float* Wu1    = (const float*)d_in[8];
    const float* bu1    = (const float*)d_in[9];
    const float* Wv1    = (const float*)d_in[10];
    const float* bv1    = (const float*)d_in[11];
    const float* Wu2    = (const float*)d_in[12];
    const float* Wv2    = (const float*)d_in[13];
    const float* P      = (const float*)d_in[14];
    const float* a      = (const float*)d_in[15];
    float* out = (float*)d_out;

    char* ws = (char*)d_ws;
    // workspace layout (bytes); total ~100 MB.
    // Overlays: codeT on UCAT (dead after k_compact);
    //           codeR on TAU+TBV (dead after k_gather2);
    //           part on CNTU+CNTV (dead after k_compact; 24.6 KB <= 32 KB);
    //           feature hi/lo splits: FUHI on IDXU, FULO on IDXV (dead after
    //             k_gather2), FVHI/FVLO on CODE (dead after k_reorder);
    //           W1 hi/lo: WU on UNN, WV on VNN (dead after k_z).
    const size_t O_CODE  = 0;                         // 16,777,216 u8
    const size_t O_CNTU  = 16777216;                  // 16,384 i32
    const size_t O_CNTV  = O_CNTU + 16384;            // 16,384 i32
    const size_t O_ACC   = O_CNTV + 16384;            // 256 B (unused)
    const size_t O_TAU   = O_ACC + 256;               // 10,485,760 f16 table (u side)
    const size_t O_TBV   = O_TAU + 10485760;          // 10,485,760 f16 table (v side)
    const size_t O_IDXU  = O_TBV + 10485760;          // 12,582,912 u16 [4096][CAP]
    const size_t O_IDXV  = O_IDXU + 12582912;         // 12,582,912 u16
    const size_t O_NNZU  = O_IDXV + 12582912;         // 16,384 i32
    const size_t O_NNZV  = O_NNZU + 16384;            // 16,384 i32
    const size_t O_RDEG  = O_NNZV + 16384;            // 16,384 f32
    const size_t O_CDEG  = O_RDEG + 16384;            // 16,384 f32
    const size_t O_UNN   = O_CDEG + 16384;            // 4,194,304 f32
    const size_t O_VNN   = O_UNN + 4194304;           // 4,194,304 f32
    const size_t O_UCAT  = O_VNN + 4194304;           // 12,582,912 f32 [4096][768]
    const size_t O_VCAT  = O_UCAT + 12582912;         // 12,582,912 f32
    const size_t O_UH    = O_VCAT + 12582912;         // 2,097,152 f32
    const size_t O_VHB   = O_UH + 2097152;            // 1,048,576 bf16 [4096][128]
    const size_t O_PT    = O_VHB + 1048576;           // 131,072 f32
    const size_t O_TB    = O_PT + 131072;             // 2,097,152 bf16 [2][4096][128]
    const size_t O_CODET = O_UCAT;                    // overlay
    const size_t O_CODER = O_TAU;                     // overlay (fits TAU+TBV)
    const size_t O_PART  = O_CNTU;                    // overlay (cnt dead after compact)
    const size_t O_FUHI  = O_IDXU;                    // overlay, 8,388,608 bf16hi
    const size_t O_FULO  = O_IDXV;                    // overlay, 8,388,608 bf16lo
    const size_t O_FVHI  = O_CODE;                    // overlay, 8,388,608
    const size_t O_FVLO  = O_CODE + 8388608;          // overlay, 8,388,608 (fits 16.77MB exactly)
    const size_t O_WUHI  = O_UNN;                     // overlay, 1,048,576
    const size_t O_WULO  = O_UNN + 1048576;           // overlay, 1,048,576
    const size_t O_WVHI  = O_VNN;                     // overlay, 1,048,576
    const size_t O_WVLO  = O_VNN + 1048576;           // overlay, 1,048,576

    uint8_t* code  = (uint8_t*)(ws + O_CODE);
    uint8_t* codeT = (uint8_t*)(ws + O_CODET);
    uint8_t* codeR = (uint8_t*)(ws + O_CODER);
    int* cnt_u = (int*)(ws + O_CNTU);
    int* cnt_v = (int*)(ws + O_CNTV);
    unsigned short* T_Au = (unsigned short*)(ws + O_TAU);
    unsigned short* T_Bv = (unsigned short*)(ws + O_TBV);
    unsigned short* idxU = (unsigned short*)(ws + O_IDXU);
    unsigned short* idxV = (unsigned short*)(ws + O_IDXV);
    int* nnzU = (int*)(ws + O_NNZU);
    int* nnzV = (int*)(ws + O_NNZV);
    float* rowDeg = (float*)(ws + O_RDEG);
    float* colDeg = (float*)(ws + O_CDEG);
    float* u_nn = (float*)(ws + O_UNN);
    float* v_nn = (float*)(ws + O_VNN);
    float* ucat = (float*)(ws + O_UCAT);
    float* vcat = (float*)(ws + O_VCAT);
    float* uh = (float*)(ws + O_UH);
    unsigned short* vhb = (unsigned short*)(ws + O_VHB);
    float* Pt = (float*)(ws + O_PT);
    unsigned short* tb = (unsigned short*)(ws + O_TB);
    float* part = (float*)(ws + O_PART);
    unsigned short* fuhi = (unsigned short*)(ws + O_FUHI);
    unsigned short* fulo = (unsigned short*)(ws + O_FULO);
    unsigned short* fvhi = (unsigned short*)(ws + O_FVHI);
    unsigned short* fvlo = (unsigned short*)(ws + O_FVLO);
    unsigned short* wuhi = (unsigned short*)(ws + O_WUHI);
    unsigned short* wulo = (unsigned short*)(ws + O_WULO);
    unsigned short* wvhi = (unsigned short*)(ws + O_WVHI);
    unsigned short* wvlo = (unsigned short*)(ws + O_WVLO);

    hipMemsetAsync(ws + O_CNTU, 0, 16384 + 16384, stream);

    k_counts<<<16, 256, 0, stream>>>(u, v, cnt_u, cnt_v);
    k_code<<<16384, 256, 0, stream>>>(adj, (uchar4*)code);
    k_transpose<<<dim3(64, 64), 256, 0, stream>>>(code, codeT);
    k_wcumsum<<<N4, 256, 0, stream>>>(u_w, cnt_u, T_Au);
    k_wcumsum<<<N4, 256, 0, stream>>>(v_w, cnt_v, T_Bv);
    k_compact<<<N4, 256, 0, stream>>>(code, cnt_v, idxU, nnzU, rowDeg);
    k_compact<<<N4, 256, 0, stream>>>(codeT, cnt_u, idxV, nnzV, colDeg);
    k_gather2<<<N4, 256, 0, stream>>>(idxU, nnzU, T_Bv, u_nn);
    k_gather2<<<N4, 256, 0, stream>>>(idxV, nnzV, T_Au, v_nn);
    // tables now dead -> build codeR over them
    k_reorder<<<N4, 256, 0, stream>>>(code, u, v, codeR);
    k_z<<<N4, 256, 0, stream>>>(u_nn, u, v, colDeg, ucat);
    k_z<<<N4, 256, 0, stream>>>(v_nn, v, u, rowDeg, vcat);
    // split fp32 -> bf16 hi/lo (overlay regions now dead)
    k_split<<<4096, 256, 0, stream>>>(u_feat, fuhi, fulo);        // 4096*1024
    k_split<<<4096, 256, 0, stream>>>(v_feat, fvhi, fvlo);
    k_split<<<512, 256, 0, stream>>>(Wu1, wuhi, wulo);            // 512*1024
    k_split<<<512, 256, 0, stream>>>(Wv1, wvhi, wvlo);
    // u_f = relu(u_features[u] @ Wu1^T + bu1) -> ucat[:, 256:768] via MFMA
    k_l1gemm<<<dim3(8, 64), 256, 0, stream>>>(fuhi, fulo, u, wuhi, wulo, bu1, ucat + H0);
    k_l1gemm<<<dim3(8, 64), 256, 0, stream>>>(fvhi, fvlo, v, wvhi, wvlo, bv1, vcat + H0);
    // u_h = relu(ucat @ Wu2^T) -> fp32 (feeds tbuf GEMM)
    k_gemm<64, 32, 16, 4, 2, false, false, true, false>
        <<<dim3(64, 4, 1), 256, 0, stream>>>(ucat, HCAT, nullptr, Wu2, HCAT, nullptr,
                                             uh, H1, HCAT, 0, 0);
    // v_h = relu(vcat @ Wv2^T) -> bf16 directly
    k_gemm<64, 32, 16, 4, 2, false, false, true, true>
        <<<dim3(64, 4, 1), 256, 0, stream>>>(vcat, HCAT, nullptr, Wv2, HCAT, nullptr,
                                             (float*)vhb, H1, HCAT, 0, 0);
    k_Pt<<<128, 256, 0, stream>>>(P, Pt);
    // t[b] = uh @ P[b] -> bf16 directly
    k_gemm<64, 32, 16, 4, 2, false, false, false, true>
        <<<dim3(64, 4, 2), 256, 0, stream>>>(uh, H1, nullptr, Pt, H1, nullptr,
                                             (float*)tb, H1, H1,
                                             (size_t)H1 * H1, (size_t)N4 * H1);
    k_scores3<<<dim3(32, 64), 256, 0, stream>>>(tb, vhb, codeR, a, out, part);
    k_finalize<<<1, 256, 0, stream>>>(part, out);
}